// Round 4
// baseline (6892.837 us; speedup 1.0000x reference)
//
#include <hip/hip_runtime.h>
#include <hip/hip_bf16.h>
#include <stdint.h>

typedef unsigned long long ull;
#define IDX_BITS 22
#define IDX_MASK 0x3FFFFFu

__device__ __forceinline__ float bfq(float x) {  // bf16-quantize (matches bf16-rounded ref)
    return __bfloat162float(__float2bfloat16(x));
}

// stats[0]=cnt_u8 stats[1]=cnt_u16 stats[2]=cnt_u32 stats[3]=mode stats[4]=C(valid count)
__global__ void k_count8(const int* __restrict__ src, const int* __restrict__ dst,
                         const unsigned char* __restrict__ det, int E, int* __restrict__ stats) {
    int e = blockIdx.x * blockDim.x + threadIdx.x;
    bool v = false;
    if (e < E) {
        int s = src[e], d = dst[e];
        v = (s > d) && (det[s] != 0) && (det[d] != 0);
    }
    ull b = __ballot(v);
    if ((threadIdx.x & 63) == 0 && b) atomicAdd(&stats[0], (int)__popcll(b));
}

__global__ void k_count16(const int* __restrict__ src, const int* __restrict__ dst,
                          const unsigned short* __restrict__ det, int E, int* __restrict__ stats) {
    if (stats[3] != -1) return;
    int e = blockIdx.x * blockDim.x + threadIdx.x;
    bool v = false;
    if (e < E) {
        int s = src[e], d = dst[e];
        v = (s > d) && (det[s] != 0) && (det[d] != 0);
    }
    ull b = __ballot(v);
    if ((threadIdx.x & 63) == 0 && b) atomicAdd(&stats[1], (int)__popcll(b));
}

__global__ void k_count32(const int* __restrict__ src, const int* __restrict__ dst,
                          const unsigned int* __restrict__ det, int E, int* __restrict__ stats) {
    if (stats[3] != -2) return;
    int e = blockIdx.x * blockDim.x + threadIdx.x;
    bool v = false;
    if (e < E) {
        int s = src[e], d = dst[e];
        v = (s > d) && (det[s] != 0) && (det[d] != 0);
    }
    ull b = __ballot(v);
    if ((threadIdx.x & 63) == 0 && b) atomicAdd(&stats[2], (int)__popcll(b));
}

__global__ void k_mode(int* stats, int osz, int step) {
    if (step == 1) {
        int c = stats[0];
        stats[3] = (c == osz / 2 || c == osz) ? 0 : -1;
    } else if (step == 2) {
        if (stats[3] == -1) {
            int c = stats[1];
            stats[3] = (c == osz / 2 || c == osz) ? 2 : -2;
        }
    } else {
        if (stats[3] == -2) stats[3] = 1;
        int m = stats[3];
        stats[4] = (m == 0) ? stats[0] : (m == 2) ? stats[1] : stats[2];
    }
}

__device__ __forceinline__ bool det_ok(int n, const void* det, int mode) {
    if (mode == 0) return ((const unsigned char*)det)[n] != 0;
    if (mode == 2) return ((const unsigned short*)det)[n] != 0;
    return ((const unsigned int*)det)[n] != 0;
}

// ================= histogram / scan / scatter ===============================
__global__ void k_hist_dst(const int* __restrict__ dst, int* __restrict__ cnt, int E) {
    int e = blockIdx.x * blockDim.x + threadIdx.x;
    if (e < E) atomicAdd(&cnt[dst[e]], 1);
}

__global__ void k_scan(const int* __restrict__ cnt, int* __restrict__ off, int n) {
    __shared__ int sdata[1024];
    __shared__ int s_running;
    int t = threadIdx.x;
    if (t == 0) s_running = 0;
    __syncthreads();
    for (int base = 0; base < n; base += 1024) {
        int v = (base + t < n) ? cnt[base + t] : 0;
        sdata[t] = v;
        __syncthreads();
        for (int sft = 1; sft < 1024; sft <<= 1) {
            int add = (t >= sft) ? sdata[t - sft] : 0;
            __syncthreads();
            sdata[t] += add;
            __syncthreads();
        }
        int incl = sdata[t];
        int run = s_running;
        if (base + t < n) off[base + t] = run + incl - v;
        __syncthreads();
        if (t == 1023) s_running = run + incl;
        __syncthreads();
    }
    if (t == 0) off[n] = s_running;
}

__global__ void k_scatter_csr(const int* __restrict__ dst, const int* __restrict__ off,
                              int* __restrict__ cur, int* __restrict__ csr_e, int E) {
    int e = blockIdx.x * blockDim.x + threadIdx.x;
    if (e >= E) return;
    int d = dst[e];
    int p = off[d] + atomicAdd(&cur[d], 1);
    csr_e[p] = e;
}

__global__ void k_bsort32(const int* __restrict__ off, int* __restrict__ arr, int N) {
    int s = blockIdx.x * blockDim.x + threadIdx.x;
    if (s >= N) return;
    int b = off[s], e2 = off[s + 1];
    for (int i = b + 1; i < e2; ++i) {
        int key = arr[i];
        int j = i - 1;
        while (j >= b && arr[j] > key) { arr[j + 1] = arr[j]; --j; }
        arr[j + 1] = key;
    }
}

// ================= fused GraphConv: 1 wave per node =========================
template <int FIN, int FOUT>
__global__ __launch_bounds__(256) void k_gcn(
    const float* __restrict__ xin, const int* __restrict__ src, const float* __restrict__ ea,
    const int* __restrict__ doff, const int* __restrict__ csr_e,
    const float* __restrict__ Wrel, const float* __restrict__ brel,
    const float* __restrict__ Wroot, float* __restrict__ xout, int N) {
    __shared__ float aggS[4][FIN];
    __shared__ float xS[4][FIN];
    int wid = threadIdx.x >> 6, lane = threadIdx.x & 63;
    int n = blockIdx.x * 4 + wid;
    if (n < N && lane < FIN) {
        int b = doff[n], e2 = doff[n + 1];
        float a = 0.f;
        for (int j = b; j < e2; ++j) {
            int e = csr_e[j];
            float w = ea[2 * e] * ea[2 * e + 1];
            a += w * xin[(size_t)src[e] * FIN + lane];
        }
        aggS[wid][lane] = a;
        xS[wid][lane] = xin[(size_t)n * FIN + lane];
    }
    __syncthreads();
    if (n >= N) return;
    for (int o = lane; o < FOUT; o += 64) {
        float acc = brel[o];
        const float* wr = Wrel + (size_t)o * FIN;
        const float* wo = Wroot + (size_t)o * FIN;
#pragma unroll
        for (int i = 0; i < FIN; ++i) acc += wr[i] * aggS[wid][i] + wo[i] * xS[wid][i];
        xout[(size_t)n * FOUT + o] = fmaxf(acc, 0.f);
    }
}

// ================= valid-edge bucketing by src ==============================
__global__ void k_hist_src(const int* __restrict__ src, const int* __restrict__ dst,
                           const void* __restrict__ det, const int* __restrict__ stats,
                           int* __restrict__ cnt, int E) {
    int e = blockIdx.x * blockDim.x + threadIdx.x;
    if (e >= E) return;
    int s = src[e], d = dst[e];
    if (s <= d) return;
    int mode = stats[3];
    if (det_ok(s, det, mode) && det_ok(d, det, mode)) atomicAdd(&cnt[s], 1);
}

__global__ void k_scatter_ent(const int* __restrict__ src, const int* __restrict__ dst,
                              const void* __restrict__ det, const int* __restrict__ stats,
                              const int* __restrict__ off, int* __restrict__ cur,
                              ull* __restrict__ ent, int E, int Mcap) {
    int e = blockIdx.x * blockDim.x + threadIdx.x;
    if (e >= E) return;
    int s = src[e], d = dst[e];
    if (s <= d) return;
    int mode = stats[3];
    if (det_ok(s, det, mode) && det_ok(d, det, mode)) {
        int p = off[s] + atomicAdd(&cur[s], 1);
        if (p < Mcap) ent[p] = ((ull)(unsigned)d << IDX_BITS) | (unsigned)e;
    }
}

__global__ void k_bsort64(const int* __restrict__ off, ull* __restrict__ ent, int N, int Mcap) {
    int s = blockIdx.x * blockDim.x + threadIdx.x;
    if (s >= N) return;
    int b = off[s], e2 = off[s + 1];
    if (e2 > Mcap) e2 = Mcap;
    for (int i = b + 1; i < e2; ++i) {
        ull key = ent[i];
        int j = i - 1;
        while (j >= b && ent[j] > key) { ent[j + 1] = ent[j]; --j; }
        ent[j + 1] = key;
    }
}

// ================= MLP over sorted valid edges ==============================
#define EPW 8
__global__ __launch_bounds__(256) void k_mlp(
    const float* __restrict__ x3, const float* __restrict__ ea,
    const int* __restrict__ src, const int* __restrict__ dst,
    const ull* __restrict__ ent, const int* __restrict__ stats,
    const float* __restrict__ W0, const float* __restrict__ b0,
    const float* __restrict__ W1, const float* __restrict__ b1,
    const float* __restrict__ W2, const float* __restrict__ b2,
    float* __restrict__ scores) {
    int M = stats[4];
    __shared__ float feat[4][EPW][257];
    __shared__ float h0s[4][EPW][128];
    int wid = threadIdx.x >> 6, lane = threadIdx.x & 63;
    if (blockIdx.x * 4 * EPW >= M) return;  // block-uniform exit only
    int m0 = (blockIdx.x * 4 + wid) * EPW;

    for (int j = 0; j < EPW; ++j) {
        int m = m0 + j;
        if (m < M) {
            int e = (int)(ent[m] & IDX_MASK);
            int s = src[e], d = dst[e];
            for (int k = lane; k < 257; k += 64) {
                float v;
                if (k < 128) v = x3[(size_t)s * 128 + k];
                else if (k == 128) v = ea[2 * e];
                else v = x3[(size_t)d * 128 + (k - 129)];
                feat[wid][j][k] = v;
            }
        } else {
            for (int k = lane; k < 257; k += 64) feat[wid][j][k] = 0.f;
        }
    }
    __syncthreads();

    {   // fc0: lane owns rows lane and lane+64 of W0 [128,257]
        float a0[EPW], a1[EPW];
        float bb0 = b0[lane], bb1 = b0[lane + 64];
        for (int j = 0; j < EPW; ++j) { a0[j] = bb0; a1[j] = bb1; }
        const float* r0 = W0 + (size_t)lane * 257;
        const float* r1 = W0 + (size_t)(lane + 64) * 257;
        for (int k = 0; k < 257; ++k) {
            float w0 = r0[k], w1 = r1[k];
#pragma unroll
            for (int j = 0; j < EPW; ++j) {
                float f = feat[wid][j][k];
                a0[j] += w0 * f;
                a1[j] += w1 * f;
            }
        }
        for (int j = 0; j < EPW; ++j) {
            h0s[wid][j][lane] = fmaxf(a0[j], 0.f);
            h0s[wid][j][lane + 64] = fmaxf(a1[j], 0.f);
        }
    }
    __syncthreads();

    float h1v[EPW];
    {   // fc1: lane owns row lane of W1 [64,128]
        float acc[EPW];
        float bb = b1[lane];
        for (int j = 0; j < EPW; ++j) acc[j] = bb;
        const float* r = W1 + (size_t)lane * 128;
        for (int k = 0; k < 128; ++k) {
            float wv = r[k];
#pragma unroll
            for (int j = 0; j < EPW; ++j) acc[j] += wv * h0s[wid][j][k];
        }
        for (int j = 0; j < EPW; ++j) h1v[j] = fmaxf(acc[j], 0.f);
    }

    float ow = W2[lane];
    float bout = b2[0];
    for (int j = 0; j < EPW; ++j) {
        float v = ow * h1v[j];
        for (int sft = 32; sft >= 1; sft >>= 1) v += __shfl_xor(v, sft);
        if (lane == 0) {
            int m = m0 + j;
            if (m < M) scores[m] = v + bout;
        }
    }
}

// ================= pairing / argmin / output (FLOAT32 out) ==================
// out (f32): [e_src(Mh) | e_dst(Mh) | sigmoid(Mh) | cls(Mh)], Mh = C/2
__global__ void k_pair(const ull* __restrict__ ent, const float* __restrict__ scores,
                       const int* __restrict__ src, const int* __restrict__ dst,
                       const float* __restrict__ ea, const int* __restrict__ stats,
                       float* __restrict__ out) {
    int C = stats[4];
    int Mh = C >> 1;
    int p = blockIdx.x * blockDim.x + threadIdx.x;
    if (p >= Mh) return;
    int e0 = (int)(ent[2 * p] & IDX_MASK);
    int e1 = (int)(ent[2 * p + 1] & IDX_MASK);
    float s0 = scores[2 * p], s1 = scores[2 * p + 1];
    int pick = (s1 < s0) ? 1 : 0;  // argmin, first index wins ties
    float sel = pick ? s1 : s0;
    int ep = pick ? e1 : e0;
    float cls = ea[2 * ep + 1];
    float sig = 1.f / (1.f + expf(-sel));
    out[p] = bfq((float)src[e0]);
    out[Mh + p] = bfq((float)dst[e0]);
    out[2 * Mh + p] = bfq(sig);
    out[3 * Mh + p] = bfq(cls);
}

extern "C" void kernel_launch(void* const* d_in, const int* in_sizes, int n_in,
                              void* d_out, int out_size, void* d_ws, size_t ws_size,
                              hipStream_t stream) {
    const float* x0 = (const float*)d_in[0];
    const int* edges = (const int*)d_in[1];
    const float* ea = (const float*)d_in[2];
    const void* det = d_in[3];

    int N = in_sizes[0] / 5;   // 50000
    int E = in_sizes[1] / 2;   // 1.6M
    int osz = out_size;
    int Ccap = osz;            // C is osz/2 (expected) -> osz is a safe cap

    const int* src = edges;
    const int* dst = edges + E;

    // -------- workspace map (~55 MB) --------
    char* p = (char*)d_ws;
    auto alloc = [&](size_t bytes) {
        char* r = p;
        p += (bytes + 255) & ~(size_t)255;
        return r;
    };
    float* xbig = (float*)alloc((size_t)N * 128 * 4);
    float* xsmall = (float*)alloc((size_t)N * 64 * 4);
    int* stats = (int*)alloc(256);
    char* u0 = p;
    // phase 1
    int* dcnt = (int*)alloc((size_t)N * 4);
    int* doff = (int*)alloc((size_t)(N + 1) * 4);
    int* dcur = (int*)alloc((size_t)N * 4);
    int* csr_e = (int*)alloc((size_t)E * 4);
    char* endB = p;
    // phase 2 (aliases phase 1)
    p = u0;
    int* scnt = (int*)alloc((size_t)N * 4);
    int* soff = (int*)alloc((size_t)(N + 1) * 4);
    int* scur = (int*)alloc((size_t)N * 4);
    ull* ent = (ull*)alloc((size_t)Ccap * 8);
    float* scores = (float*)alloc((size_t)Ccap * 4);
    char* endC = p;
    size_t need = (size_t)(((endB > endC) ? endB : endC) - (char*)d_ws);
    if (need > ws_size) return;  // signature: absmax == 49920.0 exactly

    const int B = 256;
    int gE = (E + B - 1) / B;

    hipMemsetAsync(stats, 0, 256, stream);
    hipMemsetAsync(dcnt, 0, (size_t)N * 4, stream);
    hipMemsetAsync(dcur, 0, (size_t)N * 4, stream);

    // detector dtype detection (gated, OOB-safe)
    k_count8<<<gE, B, 0, stream>>>(src, dst, (const unsigned char*)det, E, stats);
    k_mode<<<1, 1, 0, stream>>>(stats, osz, 1);
    k_count16<<<gE, B, 0, stream>>>(src, dst, (const unsigned short*)det, E, stats);
    k_mode<<<1, 1, 0, stream>>>(stats, osz, 2);
    k_count32<<<gE, B, 0, stream>>>(src, dst, (const unsigned int*)det, E, stats);
    k_mode<<<1, 1, 0, stream>>>(stats, osz, 3);

    // CSR by dst (edge indices, sorted per bucket => deterministic fp order)
    k_hist_dst<<<gE, B, 0, stream>>>(dst, dcnt, E);
    k_scan<<<1, 1024, 0, stream>>>(dcnt, doff, N);
    k_scatter_csr<<<gE, B, 0, stream>>>(dst, doff, dcur, csr_e, E);
    k_bsort32<<<(N + B - 1) / B, B, 0, stream>>>(doff, csr_e, N);

    // 3 fused GraphConv layers: x0 -> xbig(32) -> xsmall(64) -> xbig(128)
    int gN = (N + 3) / 4;
    k_gcn<5, 32><<<gN, B, 0, stream>>>(x0, src, ea, doff, csr_e,
                                       (const float*)d_in[4], (const float*)d_in[5],
                                       (const float*)d_in[6], xbig, N);
    k_gcn<32, 64><<<gN, B, 0, stream>>>(xbig, src, ea, doff, csr_e,
                                        (const float*)d_in[7], (const float*)d_in[8],
                                        (const float*)d_in[9], xsmall, N);
    k_gcn<64, 128><<<gN, B, 0, stream>>>(xsmall, src, ea, doff, csr_e,
                                         (const float*)d_in[10], (const float*)d_in[11],
                                         (const float*)d_in[12], xbig, N);
    const float* x3 = xbig;

    // phase 2: valid edges bucketed by src, sorted by (dst, idx) within bucket
    hipMemsetAsync(scnt, 0, (size_t)N * 4, stream);
    hipMemsetAsync(scur, 0, (size_t)N * 4, stream);
    k_hist_src<<<gE, B, 0, stream>>>(src, dst, det, stats, scnt, E);
    k_scan<<<1, 1024, 0, stream>>>(scnt, soff, N);
    k_scatter_ent<<<gE, B, 0, stream>>>(src, dst, det, stats, soff, scur, ent, E, Ccap);
    k_bsort64<<<(N + B - 1) / B, B, 0, stream>>>(soff, ent, N, Ccap);

    // MLP scores
    k_mlp<<<(Ccap + 4 * EPW - 1) / (4 * EPW), 256, 0, stream>>>(
        x3, ea, src, dst, ent, stats,
        (const float*)d_in[13], (const float*)d_in[14],
        (const float*)d_in[15], (const float*)d_in[16],
        (const float*)d_in[17], (const float*)d_in[18],
        scores);

    // pairing + output (float32!)
    k_pair<<<(Ccap / 2 + B - 1) / B, B, 0, stream>>>(ent, scores, src, dst, ea, stats,
                                                     (float*)d_out);
}

// Round 5
// 2360.676 us; speedup vs baseline: 2.9199x; 2.9199x over previous
//
#include <hip/hip_runtime.h>
#include <hip/hip_bf16.h>
#include <stdint.h>

typedef unsigned long long ull;
typedef __attribute__((ext_vector_type(8))) short short8;
typedef __attribute__((ext_vector_type(4))) float f32x4;
#define IDX_BITS 22
#define IDX_MASK 0x3FFFFFu

__device__ __forceinline__ float bfq(float x) {
    return __bfloat162float(__float2bfloat16(x));
}
__device__ __forceinline__ unsigned short bfu(float x) {
    __hip_bfloat16 b = __float2bfloat16(x);
    return *(unsigned short*)&b;
}

// stats[0]=cnt_u8 stats[1]=cnt_u16 stats[2]=cnt_u32 stats[3]=mode stats[4]=C
__global__ void k_count8(const int* __restrict__ src, const int* __restrict__ dst,
                         const unsigned char* __restrict__ det, int E, int* __restrict__ stats) {
    int e = blockIdx.x * blockDim.x + threadIdx.x;
    bool v = false;
    if (e < E) {
        int s = src[e], d = dst[e];
        v = (s > d) && (det[s] != 0) && (det[d] != 0);
    }
    ull b = __ballot(v);
    if ((threadIdx.x & 63) == 0 && b) atomicAdd(&stats[0], (int)__popcll(b));
}
__global__ void k_count16(const int* __restrict__ src, const int* __restrict__ dst,
                          const unsigned short* __restrict__ det, int E, int* __restrict__ stats) {
    if (stats[3] != -1) return;
    int e = blockIdx.x * blockDim.x + threadIdx.x;
    bool v = false;
    if (e < E) {
        int s = src[e], d = dst[e];
        v = (s > d) && (det[s] != 0) && (det[d] != 0);
    }
    ull b = __ballot(v);
    if ((threadIdx.x & 63) == 0 && b) atomicAdd(&stats[1], (int)__popcll(b));
}
__global__ void k_count32(const int* __restrict__ src, const int* __restrict__ dst,
                          const unsigned int* __restrict__ det, int E, int* __restrict__ stats) {
    if (stats[3] != -2) return;
    int e = blockIdx.x * blockDim.x + threadIdx.x;
    bool v = false;
    if (e < E) {
        int s = src[e], d = dst[e];
        v = (s > d) && (det[s] != 0) && (det[d] != 0);
    }
    ull b = __ballot(v);
    if ((threadIdx.x & 63) == 0 && b) atomicAdd(&stats[2], (int)__popcll(b));
}
__global__ void k_mode(int* stats, int osz, int step) {
    if (step == 1) {
        int c = stats[0];
        stats[3] = (c == osz / 2 || c == osz) ? 0 : -1;
    } else if (step == 2) {
        if (stats[3] == -1) {
            int c = stats[1];
            stats[3] = (c == osz / 2 || c == osz) ? 2 : -2;
        }
    } else {
        if (stats[3] == -2) stats[3] = 1;
        int m = stats[3];
        stats[4] = (m == 0) ? stats[0] : (m == 2) ? stats[1] : stats[2];
    }
}
__device__ __forceinline__ bool det_ok(int n, const void* det, int mode) {
    if (mode == 0) return ((const unsigned char*)det)[n] != 0;
    if (mode == 2) return ((const unsigned short*)det)[n] != 0;
    return ((const unsigned int*)det)[n] != 0;
}

// ================= histogram / scan / scatter ===============================
__global__ void k_hist_dst(const int* __restrict__ dst, int* __restrict__ cnt, int E) {
    int e = blockIdx.x * blockDim.x + threadIdx.x;
    if (e < E) atomicAdd(&cnt[dst[e]], 1);
}

// single-block wave-shuffle exclusive scan (blockDim = 1024); off[n]=total
__global__ void k_scan(const int* __restrict__ cnt, int* __restrict__ off, int n) {
    __shared__ int wsum[16];
    __shared__ int s_run, s_tot;
    int t = threadIdx.x, lane = t & 63, w = t >> 6;
    if (t == 0) s_run = 0;
    __syncthreads();
    for (int base = 0; base < n; base += 1024) {
        int v = (base + t < n) ? cnt[base + t] : 0;
        int inc = v;
#pragma unroll
        for (int s = 1; s < 64; s <<= 1) {
            int u = __shfl_up(inc, s);
            if (lane >= s) inc += u;
        }
        if (lane == 63) wsum[w] = inc;
        __syncthreads();
        if (t < 16) {
            int x = wsum[t], sc = x;
#pragma unroll
            for (int s = 1; s < 16; s <<= 1) {
                int u = __shfl_up(sc, s);
                if (t >= s) sc += u;
            }
            wsum[t] = sc - x;  // exclusive
            if (t == 15) s_tot = sc;
        }
        __syncthreads();
        int run = s_run;
        if (base + t < n) off[base + t] = run + wsum[w] + inc - v;
        __syncthreads();
        if (t == 0) s_run = run + s_tot;
        __syncthreads();
    }
    if (t == 0) off[n] = s_run;
}

__global__ void k_scatter_csr(const int* __restrict__ dst, const int* __restrict__ off,
                              int* __restrict__ cur, int* __restrict__ csr_e, int E) {
    int e = blockIdx.x * blockDim.x + threadIdx.x;
    if (e >= E) return;
    int d = dst[e];
    int p = off[d] + atomicAdd(&cur[d], 1);
    csr_e[p] = e;
}

// ================= weight prep ==============================================
__global__ void k_tr(const float* __restrict__ in, float* __restrict__ out, int O, int I) {
    int idx = blockIdx.x * blockDim.x + threadIdx.x;
    if (idx < O * I) {
        int o = idx / I, i = idx % I;
        out[i * O + o] = in[idx];
    }
}

// pack W0 [128,257] and W1 [64,128] into MFMA B-fragment order (bf16)
// feat permutation: k<128 -> xsrc k; 128..255 -> xdst (orig k+1); 256 -> ea0 (orig 128); 257+ -> 0
__global__ void k_wfrag(const float* __restrict__ W0, const float* __restrict__ W1,
                        unsigned short* __restrict__ w0f, unsigned short* __restrict__ w1f) {
    int idx = blockIdx.x * blockDim.x + threadIdx.x;
    const int N0 = 9 * 8 * 64 * 8;
    if (idx < N0) {
        int j = idx & 7, l = (idx >> 3) & 63, ct = (idx >> 9) & 7, ks = idx >> 12;
        int k = ks * 32 + ((l >> 4) << 3) + j;
        int col = ct * 16 + (l & 15);
        int ko = (k < 128) ? k : (k < 256) ? (k + 1) : (k == 256) ? 128 : -1;
        float v = (ko >= 0) ? W0[col * 257 + ko] : 0.f;
        w0f[idx] = bfu(v);
    } else {
        int i2 = idx - N0;
        if (i2 < 4 * 4 * 64 * 8) {
            int j = i2 & 7, l = (i2 >> 3) & 63, ct = (i2 >> 9) & 3, ks = i2 >> 11;
            int k = ks * 32 + ((l >> 4) << 3) + j;
            int col = ct * 16 + (l & 15);
            w1f[i2] = bfu(W1[col * 128 + k]);
        }
    }
}

// ================= fused GraphConv: 1 wave per node =========================
template <int FIN, int FOUT, bool BF16OUT>
__global__ __launch_bounds__(256) void k_gcn(
    const float* __restrict__ xin, const int* __restrict__ src, const float* __restrict__ ea,
    const int* __restrict__ doff, const int* __restrict__ csr_e,
    const float* __restrict__ WrelT, const float* __restrict__ brel,
    const float* __restrict__ WrootT, void* __restrict__ xout, int N) {
    __shared__ float aggS[4][FIN];
    __shared__ float xS[4][FIN];
    int wid = threadIdx.x >> 6, lane = threadIdx.x & 63;
    int n = blockIdx.x * 4 + wid;
    if (n < N && lane < FIN) {
        int b = doff[n], e2 = doff[n + 1];
        float a = 0.f;
        for (int j = b; j < e2; ++j) {
            int e = csr_e[j];
            float w = ea[2 * e] * ea[2 * e + 1];
            a += w * xin[(size_t)src[e] * FIN + lane];
        }
        aggS[wid][lane] = a;
        xS[wid][lane] = xin[(size_t)n * FIN + lane];
    }
    __syncthreads();
    if (n >= N) return;
    for (int o = lane; o < FOUT; o += 64) {
        float acc = brel[o];
#pragma unroll
        for (int i = 0; i < FIN; ++i)
            acc += WrelT[i * FOUT + o] * aggS[wid][i] + WrootT[i * FOUT + o] * xS[wid][i];
        acc = fmaxf(acc, 0.f);
        if (BF16OUT)
            ((unsigned short*)xout)[(size_t)n * FOUT + o] = bfu(acc);
        else
            ((float*)xout)[(size_t)n * FOUT + o] = acc;
    }
}

// ================= valid-edge bucketing by src ==============================
__global__ void k_hist_src(const int* __restrict__ src, const int* __restrict__ dst,
                           const void* __restrict__ det, const int* __restrict__ stats,
                           int* __restrict__ cnt, int E) {
    int e = blockIdx.x * blockDim.x + threadIdx.x;
    if (e >= E) return;
    int s = src[e], d = dst[e];
    if (s <= d) return;
    int mode = stats[3];
    if (det_ok(s, det, mode) && det_ok(d, det, mode)) atomicAdd(&cnt[s], 1);
}

__global__ void k_scatter_ent(const int* __restrict__ src, const int* __restrict__ dst,
                              const void* __restrict__ det, const int* __restrict__ stats,
                              const int* __restrict__ off, int* __restrict__ cur,
                              ull* __restrict__ ent, int E, int Mcap) {
    int e = blockIdx.x * blockDim.x + threadIdx.x;
    if (e >= E) return;
    int s = src[e], d = dst[e];
    if (s <= d) return;
    int mode = stats[3];
    if (det_ok(s, det, mode) && det_ok(d, det, mode)) {
        int p = off[s] + atomicAdd(&cur[s], 1);
        if (p < Mcap) ent[p] = ((ull)(unsigned)d << IDX_BITS) | (unsigned)e;
    }
}

__global__ void k_bsort64(const int* __restrict__ off, ull* __restrict__ ent, int N, int Mcap) {
    int s = blockIdx.x * blockDim.x + threadIdx.x;
    if (s >= N) return;
    int b = off[s], e2 = off[s + 1];
    if (e2 > Mcap) e2 = Mcap;
    for (int i = b + 1; i < e2; ++i) {
        ull key = ent[i];
        int j = i - 1;
        while (j >= b && ent[j] > key) { ent[j + 1] = ent[j]; --j; }
        ent[j + 1] = key;
    }
}

// ================= MFMA MLP: 64 edges per block =============================
// feat (permuted): [xsrc(128) | xdst(128) | ea0 | 0-pad -> 288] bf16
// fc0: [64,288]x[288,128] -> h0; fc1: [64,128]x[128,64] -> h1; dot w2 -> score
__global__ __launch_bounds__(256) void k_mlp(
    const unsigned short* __restrict__ x3b, const float* __restrict__ ea,
    const int* __restrict__ src, const int* __restrict__ dst,
    const ull* __restrict__ ent, const int* __restrict__ stats,
    const unsigned short* __restrict__ w0f, const unsigned short* __restrict__ w1f,
    const float* __restrict__ b0, const float* __restrict__ b1,
    const float* __restrict__ w2, const float* __restrict__ b2,
    float* __restrict__ scores) {
    int M = stats[4];
    int m0 = blockIdx.x * 64;
    if (m0 >= M) return;
    __shared__ unsigned short smem[64 * 296];  // featA [64][296]; later h0s [64][136]
    unsigned short* featA = smem;
    unsigned short* h0s = smem;
    int t = threadIdx.x, lane = t & 63, w = t >> 6;

    {   // stage feat: 4 threads per edge, 64 bf16 each
        int j = t >> 2, q = t & 3;
        int m = m0 + j;
        unsigned short* dp = &featA[j * 296 + q * 64];
        if (m < M) {
            int e = (int)(ent[m] & IDX_MASK);
            int node = (q < 2) ? src[e] : dst[e];
            const unsigned short* row = x3b + (size_t)node * 128 + (q & 1) * 64;
#pragma unroll
            for (int c = 0; c < 8; ++c)
                *(uint4*)&dp[c * 8] = *(const uint4*)&row[c * 8];
            if (q == 0) {
                featA[j * 296 + 256] = bfu(ea[2 * e]);
                for (int k = 257; k < 288; ++k) featA[j * 296 + k] = 0;
            }
        } else {
            uint4 z = make_uint4(0, 0, 0, 0);
#pragma unroll
            for (int c = 0; c < 8; ++c) *(uint4*)&dp[c * 8] = z;
            if (q == 0)
                for (int k = 256; k < 288; ++k) featA[j * 296 + k] = 0;
        }
    }
    __syncthreads();

    // fc0: wave w -> edge rows 16w..16w+15, all 128 cols
    f32x4 acc[8];
#pragma unroll
    for (int ct = 0; ct < 8; ++ct) acc[ct] = (f32x4){0.f, 0.f, 0.f, 0.f};
    {
        int arow = w * 16 + (lane & 15);
        int koff = (lane >> 4) << 3;
#pragma unroll
        for (int ks = 0; ks < 9; ++ks) {
            short8 a = *(const short8*)&featA[arow * 296 + ks * 32 + koff];
#pragma unroll
            for (int ct = 0; ct < 8; ++ct) {
                short8 b = ((const short8*)w0f)[(ks * 8 + ct) * 64 + lane];
                acc[ct] = __builtin_amdgcn_mfma_f32_16x16x32_bf16(a, b, acc[ct], 0, 0, 0);
            }
        }
    }
    __syncthreads();  // featA dead; smem becomes h0s

    {   // bias + ReLU -> h0s bf16 [64][136]
        int g = lane >> 4, c0 = lane & 15;
#pragma unroll
        for (int ct = 0; ct < 8; ++ct) {
            int col = ct * 16 + c0;
            float bb = b0[col];
#pragma unroll
            for (int r = 0; r < 4; ++r) {
                int rowl = w * 16 + g * 4 + r;
                h0s[rowl * 136 + col] = bfu(fmaxf(acc[ct][r] + bb, 0.f));
            }
        }
    }
    __syncthreads();

    // fc1
    f32x4 acc1[4];
#pragma unroll
    for (int ct = 0; ct < 4; ++ct) acc1[ct] = (f32x4){0.f, 0.f, 0.f, 0.f};
    {
        int arow = w * 16 + (lane & 15);
        int koff = (lane >> 4) << 3;
#pragma unroll
        for (int ks = 0; ks < 4; ++ks) {
            short8 a = *(const short8*)&h0s[arow * 136 + ks * 32 + koff];
#pragma unroll
            for (int ct = 0; ct < 4; ++ct) {
                short8 b = ((const short8*)w1f)[(ks * 4 + ct) * 64 + lane];
                acc1[ct] = __builtin_amdgcn_mfma_f32_16x16x32_bf16(a, b, acc1[ct], 0, 0, 0);
            }
        }
    }

    // bias + ReLU + dot(w2) + cross-lane reduce over the 16-lane col groups
    {
        int g = lane >> 4, c0 = lane & 15;
        float part[4] = {0.f, 0.f, 0.f, 0.f};
#pragma unroll
        for (int ct = 0; ct < 4; ++ct) {
            int col = ct * 16 + c0;
            float bb = b1[col], wv = w2[col];
#pragma unroll
            for (int r = 0; r < 4; ++r)
                part[r] += fmaxf(acc1[ct][r] + bb, 0.f) * wv;
        }
        float bout = b2[0];
#pragma unroll
        for (int r = 0; r < 4; ++r) {
            float v = part[r];
            v += __shfl_xor(v, 1);
            v += __shfl_xor(v, 2);
            v += __shfl_xor(v, 4);
            v += __shfl_xor(v, 8);
            if (c0 == 0) {
                int m = m0 + w * 16 + g * 4 + r;
                if (m < M) scores[m] = v + bout;
            }
        }
    }
}

// ================= pairing / argmin / output (f32, bf16-quantized) ==========
__global__ void k_pair(const ull* __restrict__ ent, const float* __restrict__ scores,
                       const int* __restrict__ src, const int* __restrict__ dst,
                       const float* __restrict__ ea, const int* __restrict__ stats,
                       float* __restrict__ out) {
    int C = stats[4];
    int Mh = C >> 1;
    int p = blockIdx.x * blockDim.x + threadIdx.x;
    if (p >= Mh) return;
    int e0 = (int)(ent[2 * p] & IDX_MASK);
    int e1 = (int)(ent[2 * p + 1] & IDX_MASK);
    float s0 = scores[2 * p], s1 = scores[2 * p + 1];
    int pick = (s1 < s0) ? 1 : 0;
    float sel = pick ? s1 : s0;
    int ep = pick ? e1 : e0;
    float cls = ea[2 * ep + 1];
    float sig = 1.f / (1.f + expf(-sel));
    out[p] = bfq((float)src[e0]);
    out[Mh + p] = bfq((float)dst[e0]);
    out[2 * Mh + p] = bfq(sig);
    out[3 * Mh + p] = bfq(cls);
}

extern "C" void kernel_launch(void* const* d_in, const int* in_sizes, int n_in,
                              void* d_out, int out_size, void* d_ws, size_t ws_size,
                              hipStream_t stream) {
    const float* x0 = (const float*)d_in[0];
    const int* edges = (const int*)d_in[1];
    const float* ea = (const float*)d_in[2];
    const void* det = d_in[3];

    int N = in_sizes[0] / 5;
    int E = in_sizes[1] / 2;
    int osz = out_size;
    int Ccap = osz;

    const int* src = edges;
    const int* dst = edges + E;

    char* p = (char*)d_ws;
    auto alloc = [&](size_t bytes) {
        char* r = p;
        p += (bytes + 255) & ~(size_t)255;
        return r;
    };
    float* xa = (float*)alloc((size_t)N * 32 * 4);            // layer1 out
    float* xb = (float*)alloc((size_t)N * 64 * 4);            // layer2 out
    unsigned short* x3b = (unsigned short*)alloc((size_t)N * 128 * 2);  // layer3 out bf16
    float* wT[6];
    int trO[6] = {32, 32, 64, 64, 128, 128};
    int trI[6] = {5, 5, 32, 32, 64, 64};
    for (int i = 0; i < 6; ++i) wT[i] = (float*)alloc((size_t)trO[i] * trI[i] * 4);
    unsigned short* w0f = (unsigned short*)alloc(9 * 8 * 64 * 8 * 2);
    unsigned short* w1f = (unsigned short*)alloc(4 * 4 * 64 * 8 * 2);
    int* stats = (int*)alloc(256);
    char* u0 = p;
    // phase 1
    int* dcnt = (int*)alloc((size_t)N * 4);
    int* doff = (int*)alloc((size_t)(N + 1) * 4);
    int* dcur = (int*)alloc((size_t)N * 4);
    int* csr_e = (int*)alloc((size_t)E * 4);
    char* endB = p;
    // phase 2 (aliases phase 1)
    p = u0;
    int* scnt = (int*)alloc((size_t)N * 4);
    int* soff = (int*)alloc((size_t)(N + 1) * 4);
    int* scur = (int*)alloc((size_t)N * 4);
    ull* ent = (ull*)alloc((size_t)Ccap * 8);
    float* scores = (float*)alloc((size_t)Ccap * 4);
    char* endC = p;
    size_t need = (size_t)(((endB > endC) ? endB : endC) - (char*)d_ws);
    if (need > ws_size) return;  // signature: absmax == 49920.0 exactly

    const int B = 256;
    int gE = (E + B - 1) / B;

    hipMemsetAsync(stats, 0, 256, stream);
    hipMemsetAsync(dcnt, 0, (size_t)N * 4, stream);
    hipMemsetAsync(dcur, 0, (size_t)N * 4, stream);

    // detector dtype detection (gated, OOB-safe)
    k_count8<<<gE, B, 0, stream>>>(src, dst, (const unsigned char*)det, E, stats);
    k_mode<<<1, 1, 0, stream>>>(stats, osz, 1);
    k_count16<<<gE, B, 0, stream>>>(src, dst, (const unsigned short*)det, E, stats);
    k_mode<<<1, 1, 0, stream>>>(stats, osz, 2);
    k_count32<<<gE, B, 0, stream>>>(src, dst, (const unsigned int*)det, E, stats);
    k_mode<<<1, 1, 0, stream>>>(stats, osz, 3);

    // weight prep: transposed GCN weights + MFMA fragments
    const float* Wrel[3] = {(const float*)d_in[4], (const float*)d_in[7], (const float*)d_in[10]};
    const float* Wroot[3] = {(const float*)d_in[6], (const float*)d_in[9], (const float*)d_in[12]};
    for (int L = 0; L < 3; ++L) {
        int O = trO[2 * L], I = trI[2 * L];
        k_tr<<<(O * I + B - 1) / B, B, 0, stream>>>(Wrel[L], wT[2 * L], O, I);
        k_tr<<<(O * I + B - 1) / B, B, 0, stream>>>(Wroot[L], wT[2 * L + 1], O, I);
    }
    k_wfrag<<<(9 * 8 * 64 * 8 + 4 * 4 * 64 * 8 + B - 1) / B, B, 0, stream>>>(
        (const float*)d_in[13], (const float*)d_in[15], w0f, w1f);

    // CSR by dst (unsorted buckets: fp sum order nondeterministic, tolerated)
    k_hist_dst<<<gE, B, 0, stream>>>(dst, dcnt, E);
    k_scan<<<1, 1024, 0, stream>>>(dcnt, doff, N);
    k_scatter_csr<<<gE, B, 0, stream>>>(dst, doff, dcur, csr_e, E);

    // 3 fused GraphConv layers
    int gN = (N + 3) / 4;
    k_gcn<5, 32, false><<<gN, B, 0, stream>>>(x0, src, ea, doff, csr_e,
                                              wT[0], (const float*)d_in[5], wT[1], xa, N);
    k_gcn<32, 64, false><<<gN, B, 0, stream>>>(xa, src, ea, doff, csr_e,
                                               wT[2], (const float*)d_in[8], wT[3], xb, N);
    k_gcn<64, 128, true><<<gN, B, 0, stream>>>(xb, src, ea, doff, csr_e,
                                               wT[4], (const float*)d_in[11], wT[5], x3b, N);

    // phase 2: valid edges bucketed by src, sorted by (dst, idx) within bucket
    hipMemsetAsync(scnt, 0, (size_t)N * 4, stream);
    hipMemsetAsync(scur, 0, (size_t)N * 4, stream);
    k_hist_src<<<gE, B, 0, stream>>>(src, dst, det, stats, scnt, E);
    k_scan<<<1, 1024, 0, stream>>>(scnt, soff, N);
    k_scatter_ent<<<gE, B, 0, stream>>>(src, dst, det, stats, soff, scur, ent, E, Ccap);
    k_bsort64<<<(N + B - 1) / B, B, 0, stream>>>(soff, ent, N, Ccap);

    // MFMA MLP
    k_mlp<<<(Ccap + 63) / 64, 256, 0, stream>>>(
        x3b, ea, src, dst, ent, stats, w0f, w1f,
        (const float*)d_in[14], (const float*)d_in[16],
        (const float*)d_in[17], (const float*)d_in[18],
        scores);

    // pairing + output
    k_pair<<<(Ccap / 2 + B - 1) / B, B, 0, stream>>>(ent, scores, src, dst, ea, stats,
                                                     (float*)d_out);
}

// Round 6
// 1550.650 us; speedup vs baseline: 4.4451x; 1.5224x over previous
//
#include <hip/hip_runtime.h>
#include <hip/hip_bf16.h>
#include <stdint.h>

typedef unsigned long long ull;
typedef __attribute__((ext_vector_type(8))) short short8;
typedef __attribute__((ext_vector_type(4))) float f32x4;
#define IDX_BITS 22
#define IDX_MASK 0x3FFFFFu

__device__ __forceinline__ float bfq(float x) {
    return __bfloat162float(__float2bfloat16(x));
}
__device__ __forceinline__ unsigned short bfu(float x) {
    __hip_bfloat16 b = __float2bfloat16(x);
    return *(unsigned short*)&b;
}
__device__ __forceinline__ float ldx(const float* p, size_t i) { return p[i]; }
__device__ __forceinline__ float ldx(const unsigned short* p, size_t i) {
    unsigned short u = p[i];
    return __bfloat162float(*(__hip_bfloat16*)&u);
}
__device__ __forceinline__ void st(float* p, size_t i, float v) { p[i] = v; }
__device__ __forceinline__ void st(unsigned short* p, size_t i, float v) { p[i] = bfu(v); }

// stats[0]=cnt_u8 stats[1]=cnt_u16 stats[2]=cnt_u32 stats[3]=mode stats[4]=C
__global__ void k_count8(const int* __restrict__ src, const int* __restrict__ dst,
                         const unsigned char* __restrict__ det, int E, int* __restrict__ stats) {
    int e = blockIdx.x * blockDim.x + threadIdx.x;
    bool v = false;
    if (e < E) {
        int s = src[e], d = dst[e];
        v = (s > d) && (det[s] != 0) && (det[d] != 0);
    }
    ull b = __ballot(v);
    if ((threadIdx.x & 63) == 0 && b) atomicAdd(&stats[0], (int)__popcll(b));
}
__global__ void k_count16(const int* __restrict__ src, const int* __restrict__ dst,
                          const unsigned short* __restrict__ det, int E, int* __restrict__ stats) {
    if (stats[3] != -1) return;
    int e = blockIdx.x * blockDim.x + threadIdx.x;
    bool v = false;
    if (e < E) {
        int s = src[e], d = dst[e];
        v = (s > d) && (det[s] != 0) && (det[d] != 0);
    }
    ull b = __ballot(v);
    if ((threadIdx.x & 63) == 0 && b) atomicAdd(&stats[1], (int)__popcll(b));
}
__global__ void k_count32(const int* __restrict__ src, const int* __restrict__ dst,
                          const unsigned int* __restrict__ det, int E, int* __restrict__ stats) {
    if (stats[3] != -2) return;
    int e = blockIdx.x * blockDim.x + threadIdx.x;
    bool v = false;
    if (e < E) {
        int s = src[e], d = dst[e];
        v = (s > d) && (det[s] != 0) && (det[d] != 0);
    }
    ull b = __ballot(v);
    if ((threadIdx.x & 63) == 0 && b) atomicAdd(&stats[2], (int)__popcll(b));
}
__global__ void k_mode(int* stats, int osz, int step) {
    if (step == 1) {
        int c = stats[0];
        stats[3] = (c == osz / 2 || c == osz) ? 0 : -1;
    } else if (step == 2) {
        if (stats[3] == -1) {
            int c = stats[1];
            stats[3] = (c == osz / 2 || c == osz) ? 2 : -2;
        }
    } else {
        if (stats[3] == -2) stats[3] = 1;
        int m = stats[3];
        stats[4] = (m == 0) ? stats[0] : (m == 2) ? stats[1] : stats[2];
    }
}
__device__ __forceinline__ bool det_ok(int n, const void* det, int mode) {
    if (mode == 0) return ((const unsigned char*)det)[n] != 0;
    if (mode == 2) return ((const unsigned short*)det)[n] != 0;
    return ((const unsigned int*)det)[n] != 0;
}

// ================= histogram / scan / scatter ===============================
__global__ void k_hist_dst(const int* __restrict__ dst, int* __restrict__ cnt, int E) {
    int e = blockIdx.x * blockDim.x + threadIdx.x;
    if (e < E) atomicAdd(&cnt[dst[e]], 1);
}

__global__ void k_scan(const int* __restrict__ cnt, int* __restrict__ off, int n) {
    __shared__ int wsum[16];
    __shared__ int s_run, s_tot;
    int t = threadIdx.x, lane = t & 63, w = t >> 6;
    if (t == 0) s_run = 0;
    __syncthreads();
    for (int base = 0; base < n; base += 1024) {
        int v = (base + t < n) ? cnt[base + t] : 0;
        int inc = v;
#pragma unroll
        for (int s = 1; s < 64; s <<= 1) {
            int u = __shfl_up(inc, s);
            if (lane >= s) inc += u;
        }
        if (lane == 63) wsum[w] = inc;
        __syncthreads();
        if (t < 16) {
            int x = wsum[t], sc = x;
#pragma unroll
            for (int s = 1; s < 16; s <<= 1) {
                int u = __shfl_up(sc, s);
                if (t >= s) sc += u;
            }
            wsum[t] = sc - x;
            if (t == 15) s_tot = sc;
        }
        __syncthreads();
        int run = s_run;
        if (base + t < n) off[base + t] = run + wsum[w] + inc - v;
        __syncthreads();
        if (t == 0) s_run = run + s_tot;
        __syncthreads();
    }
    if (t == 0) off[n] = s_run;
}

__global__ void k_scatter_csr(const int* __restrict__ dst, const int* __restrict__ off,
                              int* __restrict__ cur, int* __restrict__ csr_e, int E) {
    int e = blockIdx.x * blockDim.x + threadIdx.x;
    if (e >= E) return;
    int d = dst[e];
    int p = off[d] + atomicAdd(&cur[d], 1);
    csr_e[p] = e;
}

// epair[j] = {src node, edge weight bits} in CSR order (kills the index chain)
__global__ void k_epair(const int* __restrict__ src, const float* __restrict__ ea,
                        const int* __restrict__ csr_e, int2* __restrict__ epair, int E) {
    int j = blockIdx.x * blockDim.x + threadIdx.x;
    if (j < E) {
        int e = csr_e[j];
        epair[j] = make_int2(src[e], __float_as_int(ea[2 * e] * ea[2 * e + 1]));
    }
}

// ================= weight prep ==============================================
__global__ void k_tr(const float* __restrict__ in, float* __restrict__ out, int O, int I) {
    int idx = blockIdx.x * blockDim.x + threadIdx.x;
    if (idx < O * I) {
        int o = idx / I, i = idx % I;
        out[i * O + o] = in[idx];
    }
}

// pack W0 [128,257] and W1 [64,128] into MFMA B-fragment order (bf16)
__global__ void k_wfrag(const float* __restrict__ W0, const float* __restrict__ W1,
                        unsigned short* __restrict__ w0f, unsigned short* __restrict__ w1f) {
    int idx = blockIdx.x * blockDim.x + threadIdx.x;
    const int N0 = 9 * 8 * 64 * 8;
    if (idx < N0) {
        int j = idx & 7, l = (idx >> 3) & 63, ct = (idx >> 9) & 7, ks = idx >> 12;
        int k = ks * 32 + ((l >> 4) << 3) + j;
        int col = ct * 16 + (l & 15);
        int ko = (k < 128) ? k : (k < 256) ? (k + 1) : (k == 256) ? 128 : -1;
        float v = (ko >= 0) ? W0[col * 257 + ko] : 0.f;
        w0f[idx] = bfu(v);
    } else {
        int i2 = idx - N0;
        if (i2 < 4 * 4 * 64 * 8) {
            int j = i2 & 7, l = (i2 >> 3) & 63, ct = (i2 >> 9) & 3, ks = i2 >> 11;
            int k = ks * 32 + ((l >> 4) << 3) + j;
            int col = ct * 16 + (l & 15);
            w1f[i2] = bfu(W1[col * 128 + k]);
        }
    }
}

// ================= fused GraphConv: 1 wave per node, ILP-8 gather ===========
template <int FIN, int FOUT, typename TIN, typename TOUT>
__global__ __launch_bounds__(256) void k_gcn(
    const TIN* __restrict__ xin, const int2* __restrict__ epair,
    const int* __restrict__ doff,
    const float* __restrict__ WrelT, const float* __restrict__ brel,
    const float* __restrict__ WrootT, TOUT* __restrict__ xout, int N) {
    __shared__ float aggS[4][FIN];
    __shared__ float xS[4][FIN];
    int wid = threadIdx.x >> 6, lane = threadIdx.x & 63;
    int n = blockIdx.x * 4 + wid;
    if (n < N && lane < FIN) {
        int b = doff[n], e2 = doff[n + 1];
        float a = 0.f;
        int j = b;
        for (; j + 8 <= e2; j += 8) {
            int2 pp[8];
#pragma unroll
            for (int u = 0; u < 8; ++u) pp[u] = epair[j + u];
            float xv[8];
#pragma unroll
            for (int u = 0; u < 8; ++u) xv[u] = ldx(xin, (size_t)pp[u].x * FIN + lane);
#pragma unroll
            for (int u = 0; u < 8; ++u) a = fmaf(__int_as_float(pp[u].y), xv[u], a);
        }
        for (; j < e2; ++j) {
            int2 pq = epair[j];
            a = fmaf(__int_as_float(pq.y), ldx(xin, (size_t)pq.x * FIN + lane), a);
        }
        aggS[wid][lane] = a;
        xS[wid][lane] = ldx(xin, (size_t)n * FIN + lane);
    }
    __syncthreads();
    if (n >= N) return;
    for (int o = lane; o < FOUT; o += 64) {
        float acc = brel[o];
#pragma unroll
        for (int i = 0; i < FIN; ++i)
            acc += WrelT[i * FOUT + o] * aggS[wid][i] + WrootT[i * FOUT + o] * xS[wid][i];
        st(xout, (size_t)n * FOUT + o, fmaxf(acc, 0.f));
    }
}

// ================= valid-edge bucketing by src ==============================
__global__ void k_hist_src(const int* __restrict__ src, const int* __restrict__ dst,
                           const void* __restrict__ det, const int* __restrict__ stats,
                           int* __restrict__ cnt, int E) {
    int e = blockIdx.x * blockDim.x + threadIdx.x;
    if (e >= E) return;
    int s = src[e], d = dst[e];
    if (s <= d) return;
    int mode = stats[3];
    if (det_ok(s, det, mode) && det_ok(d, det, mode)) atomicAdd(&cnt[s], 1);
}

__global__ void k_scatter_ent(const int* __restrict__ src, const int* __restrict__ dst,
                              const void* __restrict__ det, const int* __restrict__ stats,
                              const int* __restrict__ off, int* __restrict__ cur,
                              ull* __restrict__ ent, int E, int Mcap) {
    int e = blockIdx.x * blockDim.x + threadIdx.x;
    if (e >= E) return;
    int s = src[e], d = dst[e];
    if (s <= d) return;
    int mode = stats[3];
    if (det_ok(s, det, mode) && det_ok(d, det, mode)) {
        int p = off[s] + atomicAdd(&cur[s], 1);
        if (p < Mcap) ent[p] = ((ull)(unsigned)d << IDX_BITS) | (unsigned)e;
    }
}

__global__ void k_bsort64(const int* __restrict__ off, ull* __restrict__ ent, int N, int Mcap) {
    int s = blockIdx.x * blockDim.x + threadIdx.x;
    if (s >= N) return;
    int b = off[s], e2 = off[s + 1];
    if (e2 > Mcap) e2 = Mcap;
    for (int i = b + 1; i < e2; ++i) {
        ull key = ent[i];
        int j = i - 1;
        while (j >= b && ent[j] > key) { ent[j + 1] = ent[j]; --j; }
        ent[j + 1] = key;
    }
}

// ================= MFMA MLP: 64 edges per block =============================
__global__ __launch_bounds__(256) void k_mlp(
    const unsigned short* __restrict__ x3b, const float* __restrict__ ea,
    const int* __restrict__ src, const int* __restrict__ dst,
    const ull* __restrict__ ent, const int* __restrict__ stats,
    const unsigned short* __restrict__ w0f, const unsigned short* __restrict__ w1f,
    const float* __restrict__ b0, const float* __restrict__ b1,
    const float* __restrict__ w2, const float* __restrict__ b2,
    float* __restrict__ scores) {
    int M = stats[4];
    int m0 = blockIdx.x * 64;
    if (m0 >= M) return;
    __shared__ unsigned short smem[64 * 296];
    unsigned short* featA = smem;
    unsigned short* h0s = smem;
    int t = threadIdx.x, lane = t & 63, w = t >> 6;

    {
        int j = t >> 2, q = t & 3;
        int m = m0 + j;
        unsigned short* dp = &featA[j * 296 + q * 64];
        if (m < M) {
            int e = (int)(ent[m] & IDX_MASK);
            int node = (q < 2) ? src[e] : dst[e];
            const unsigned short* row = x3b + (size_t)node * 128 + (q & 1) * 64;
#pragma unroll
            for (int c = 0; c < 8; ++c)
                *(uint4*)&dp[c * 8] = *(const uint4*)&row[c * 8];
            if (q == 0) {
                featA[j * 296 + 256] = bfu(ea[2 * e]);
                for (int k = 257; k < 288; ++k) featA[j * 296 + k] = 0;
            }
        } else {
            uint4 z = make_uint4(0, 0, 0, 0);
#pragma unroll
            for (int c = 0; c < 8; ++c) *(uint4*)&dp[c * 8] = z;
            if (q == 0)
                for (int k = 256; k < 288; ++k) featA[j * 296 + k] = 0;
        }
    }
    __syncthreads();

    f32x4 acc[8];
#pragma unroll
    for (int ct = 0; ct < 8; ++ct) acc[ct] = (f32x4){0.f, 0.f, 0.f, 0.f};
    {
        int arow = w * 16 + (lane & 15);
        int koff = (lane >> 4) << 3;
#pragma unroll
        for (int ks = 0; ks < 9; ++ks) {
            short8 a = *(const short8*)&featA[arow * 296 + ks * 32 + koff];
#pragma unroll
            for (int ct = 0; ct < 8; ++ct) {
                short8 b = ((const short8*)w0f)[(ks * 8 + ct) * 64 + lane];
                acc[ct] = __builtin_amdgcn_mfma_f32_16x16x32_bf16(a, b, acc[ct], 0, 0, 0);
            }
        }
    }
    __syncthreads();

    {
        int g = lane >> 4, c0 = lane & 15;
#pragma unroll
        for (int ct = 0; ct < 8; ++ct) {
            int col = ct * 16 + c0;
            float bb = b0[col];
#pragma unroll
            for (int r = 0; r < 4; ++r) {
                int rowl = w * 16 + g * 4 + r;
                h0s[rowl * 136 + col] = bfu(fmaxf(acc[ct][r] + bb, 0.f));
            }
        }
    }
    __syncthreads();

    f32x4 acc1[4];
#pragma unroll
    for (int ct = 0; ct < 4; ++ct) acc1[ct] = (f32x4){0.f, 0.f, 0.f, 0.f};
    {
        int arow = w * 16 + (lane & 15);
        int koff = (lane >> 4) << 3;
#pragma unroll
        for (int ks = 0; ks < 4; ++ks) {
            short8 a = *(const short8*)&h0s[arow * 136 + ks * 32 + koff];
#pragma unroll
            for (int ct = 0; ct < 4; ++ct) {
                short8 b = ((const short8*)w1f)[(ks * 4 + ct) * 64 + lane];
                acc1[ct] = __builtin_amdgcn_mfma_f32_16x16x32_bf16(a, b, acc1[ct], 0, 0, 0);
            }
        }
    }

    {
        int g = lane >> 4, c0 = lane & 15;
        float part[4] = {0.f, 0.f, 0.f, 0.f};
#pragma unroll
        for (int ct = 0; ct < 4; ++ct) {
            int col = ct * 16 + c0;
            float bb = b1[col], wv = w2[col];
#pragma unroll
            for (int r = 0; r < 4; ++r)
                part[r] += fmaxf(acc1[ct][r] + bb, 0.f) * wv;
        }
        float bout = b2[0];
#pragma unroll
        for (int r = 0; r < 4; ++r) {
            float v = part[r];
            v += __shfl_xor(v, 1);
            v += __shfl_xor(v, 2);
            v += __shfl_xor(v, 4);
            v += __shfl_xor(v, 8);
            if (c0 == 0) {
                int m = m0 + w * 16 + g * 4 + r;
                if (m < M) scores[m] = v + bout;
            }
        }
    }
}

// ================= pairing / argmin / output ================================
__global__ void k_pair(const ull* __restrict__ ent, const float* __restrict__ scores,
                       const int* __restrict__ src, const int* __restrict__ dst,
                       const float* __restrict__ ea, const int* __restrict__ stats,
                       float* __restrict__ out) {
    int C = stats[4];
    int Mh = C >> 1;
    int p = blockIdx.x * blockDim.x + threadIdx.x;
    if (p >= Mh) return;
    int e0 = (int)(ent[2 * p] & IDX_MASK);
    int e1 = (int)(ent[2 * p + 1] & IDX_MASK);
    float s0 = scores[2 * p], s1 = scores[2 * p + 1];
    int pick = (s1 < s0) ? 1 : 0;
    float sel = pick ? s1 : s0;
    int ep = pick ? e1 : e0;
    float cls = ea[2 * ep + 1];
    float sig = 1.f / (1.f + expf(-sel));
    out[p] = bfq((float)src[e0]);
    out[Mh + p] = bfq((float)dst[e0]);
    out[2 * Mh + p] = bfq(sig);
    out[3 * Mh + p] = bfq(cls);
}

extern "C" void kernel_launch(void* const* d_in, const int* in_sizes, int n_in,
                              void* d_out, int out_size, void* d_ws, size_t ws_size,
                              hipStream_t stream) {
    const float* x0 = (const float*)d_in[0];
    const int* edges = (const int*)d_in[1];
    const float* ea = (const float*)d_in[2];
    const void* det = d_in[3];

    int N = in_sizes[0] / 5;
    int E = in_sizes[1] / 2;
    int osz = out_size;
    int Ccap = osz;

    const int* src = edges;
    const int* dst = edges + E;

    char* p = (char*)d_ws;
    auto alloc = [&](size_t bytes) {
        char* r = p;
        p += (bytes + 255) & ~(size_t)255;
        return r;
    };
    unsigned short* xa = (unsigned short*)alloc((size_t)N * 32 * 2);
    unsigned short* xb = (unsigned short*)alloc((size_t)N * 64 * 2);
    unsigned short* x3b = (unsigned short*)alloc((size_t)N * 128 * 2);
    float* wT[6];
    int trO[6] = {32, 32, 64, 64, 128, 128};
    int trI[6] = {5, 5, 32, 32, 64, 64};
    for (int i = 0; i < 6; ++i) wT[i] = (float*)alloc((size_t)trO[i] * trI[i] * 4);
    unsigned short* w0f = (unsigned short*)alloc(9 * 8 * 64 * 8 * 2);
    unsigned short* w1f = (unsigned short*)alloc(4 * 4 * 64 * 8 * 2);
    int* stats = (int*)alloc(256);
    char* u0 = p;
    // phase 1 (CSR + epair; epair live through GCN layers)
    int* dcnt = (int*)alloc((size_t)N * 4);
    int* doff = (int*)alloc((size_t)(N + 1) * 4);
    int* dcur = (int*)alloc((size_t)N * 4);
    int* csr_e = (int*)alloc((size_t)E * 4);
    int2* epair = (int2*)alloc((size_t)E * 8);
    char* endB = p;
    // phase 2 (aliases phase 1 — runs strictly after GCN layers complete)
    p = u0;
    int* scnt = (int*)alloc((size_t)N * 4);
    int* soff = (int*)alloc((size_t)(N + 1) * 4);
    int* scur = (int*)alloc((size_t)N * 4);
    ull* ent = (ull*)alloc((size_t)Ccap * 8);
    float* scores = (float*)alloc((size_t)Ccap * 4);
    char* endC = p;
    size_t need = (size_t)(((endB > endC) ? endB : endC) - (char*)d_ws);
    if (need > ws_size) return;  // signature: absmax == 49920.0 exactly

    const int B = 256;
    int gE = (E + B - 1) / B;

    hipMemsetAsync(stats, 0, 256, stream);
    hipMemsetAsync(dcnt, 0, (size_t)N * 4, stream);
    hipMemsetAsync(dcur, 0, (size_t)N * 4, stream);

    k_count8<<<gE, B, 0, stream>>>(src, dst, (const unsigned char*)det, E, stats);
    k_mode<<<1, 1, 0, stream>>>(stats, osz, 1);
    k_count16<<<gE, B, 0, stream>>>(src, dst, (const unsigned short*)det, E, stats);
    k_mode<<<1, 1, 0, stream>>>(stats, osz, 2);
    k_count32<<<gE, B, 0, stream>>>(src, dst, (const unsigned int*)det, E, stats);
    k_mode<<<1, 1, 0, stream>>>(stats, osz, 3);

    const float* Wrel[3] = {(const float*)d_in[4], (const float*)d_in[7], (const float*)d_in[10]};
    const float* Wroot[3] = {(const float*)d_in[6], (const float*)d_in[9], (const float*)d_in[12]};
    for (int L = 0; L < 3; ++L) {
        int O = trO[2 * L], I = trI[2 * L];
        k_tr<<<(O * I + B - 1) / B, B, 0, stream>>>(Wrel[L], wT[2 * L], O, I);
        k_tr<<<(O * I + B - 1) / B, B, 0, stream>>>(Wroot[L], wT[2 * L + 1], O, I);
    }
    k_wfrag<<<(9 * 8 * 64 * 8 + 4 * 4 * 64 * 8 + B - 1) / B, B, 0, stream>>>(
        (const float*)d_in[13], (const float*)d_in[15], w0f, w1f);

    // CSR by dst + epair
    k_hist_dst<<<gE, B, 0, stream>>>(dst, dcnt, E);
    k_scan<<<1, 1024, 0, stream>>>(dcnt, doff, N);
    k_scatter_csr<<<gE, B, 0, stream>>>(dst, doff, dcur, csr_e, E);
    k_epair<<<gE, B, 0, stream>>>(src, ea, csr_e, epair, E);

    // 3 fused GraphConv layers (bf16 activations)
    int gN = (N + 3) / 4;
    k_gcn<5, 32, float, unsigned short><<<gN, B, 0, stream>>>(
        x0, epair, doff, wT[0], (const float*)d_in[5], wT[1], xa, N);
    k_gcn<32, 64, unsigned short, unsigned short><<<gN, B, 0, stream>>>(
        xa, epair, doff, wT[2], (const float*)d_in[8], wT[3], xb, N);
    k_gcn<64, 128, unsigned short, unsigned short><<<gN, B, 0, stream>>>(
        xb, epair, doff, wT[4], (const float*)d_in[11], wT[5], x3b, N);

    // phase 2: valid edges bucketed by src, sorted by (dst, idx) within bucket
    hipMemsetAsync(scnt, 0, (size_t)N * 4, stream);
    hipMemsetAsync(scur, 0, (size_t)N * 4, stream);
    k_hist_src<<<gE, B, 0, stream>>>(src, dst, det, stats, scnt, E);
    k_scan<<<1, 1024, 0, stream>>>(scnt, soff, N);
    k_scatter_ent<<<gE, B, 0, stream>>>(src, dst, det, stats, soff, scur, ent, E, Ccap);
    k_bsort64<<<(N + B - 1) / B, B, 0, stream>>>(soff, ent, N, Ccap);

    // MFMA MLP
    k_mlp<<<(Ccap + 63) / 64, 256, 0, stream>>>(
        x3b, ea, src, dst, ent, stats, w0f, w1f,
        (const float*)d_in[14], (const float*)d_in[16],
        (const float*)d_in[17], (const float*)d_in[18],
        scores);

    // pairing + output
    k_pair<<<(Ccap / 2 + B - 1) / B, B, 0, stream>>>(ent, scores, src, dst, ea, stats,
                                                     (float*)d_out);
}